// Round 1
// baseline (1036.528 us; speedup 1.0000x reference)
//
#include <hip/hip_runtime.h>
#include <hip/hip_bf16.h>

#define NN 2000
#define DD 24

// Pass 1: lanes cover i (64 per block), l is wave-uniform within the loop.
// grid = (32 i-blocks, lblk l-chunks), block = 64 threads (1 wave).
// part[lb * (NN*DD) + i*DD + j] = partial sum over this block's l-range.
__global__ __launch_bounds__(64) void notears_pass1(
    const float* __restrict__ x,      // [NN, DD]
    const float* __restrict__ alpha,  // [DD, NN]
    const float* __restrict__ beta,   // [DD, DD, NN]
    float* __restrict__ part,         // [lblk, NN*DD]
    int lblk, int lch)
{
    const int lane = threadIdx.x;       // 0..63
    const int ib   = blockIdx.x;        // 0..31
    const int lb   = blockIdx.y;        // 0..lblk-1
    const int i    = ib * 64 + lane;
    const int ic   = i < NN ? i : NN - 1;

    // x_i into registers (per-lane)
    float xi[DD];
    #pragma unroll
    for (int k = 0; k < DD; ++k) xi[k] = x[ic * DD + k];

    float acc[DD];
    #pragma unroll
    for (int j = 0; j < DD; ++j) acc[j] = 0.0f;

    const int l0 = lb * lch;
    const int l1 = (l0 + lch) < NN ? (l0 + lch) : NN;

    for (int l = l0; l < l1; ++l) {
        // x_l is wave-uniform -> scalar loads
        float xl[DD];
        const float4* xr = reinterpret_cast<const float4*>(x + (size_t)l * DD);
        #pragma unroll
        for (int q = 0; q < DD / 4; ++q) {
            float4 v = xr[q];
            xl[4 * q + 0] = v.x; xl[4 * q + 1] = v.y;
            xl[4 * q + 2] = v.z; xl[4 * q + 3] = v.w;
        }

        float diff[DD];
        float S = 0.0f;
        #pragma unroll
        for (int k = 0; k < DD; ++k) {
            float d = xi[k] - xl[k];
            diff[k] = d;
            S = fmaf(d, d, S);
        }

        #pragma unroll
        for (int j = 0; j < DD; ++j) {
            float d2 = diff[j] * diff[j];
            float K  = __expf(d2 - S);   // exp(-(S - diff_j^2))
            float t  = 0.0f;
            const float* bj = beta + (size_t)j * DD * NN + l;  // beta[j, a, l], stride NN over a
            #pragma unroll
            for (int a = 0; a < DD; ++a)
                t = fmaf(bj[(size_t)a * NN], diff[a], t);
            // remove diagonal a == j
            t = fmaf(-bj[(size_t)j * NN], diff[j], t);
            acc[j] = fmaf(K, fmaf(2.0f, t, alpha[(size_t)j * NN + l]), acc[j]);
        }
    }

    if (i < NN) {
        float* p = part + (size_t)lb * (NN * DD) + (size_t)i * DD;
        #pragma unroll
        for (int q = 0; q < DD / 4; ++q) {
            float4 v;
            v.x = acc[4 * q + 0]; v.y = acc[4 * q + 1];
            v.z = acc[4 * q + 2]; v.w = acc[4 * q + 3];
            reinterpret_cast<float4*>(p)[q] = v;
        }
    }
}

// Pass 2: reduce partials over lblk slabs. One thread per (i,j).
__global__ __launch_bounds__(256) void notears_pass2(
    const float* __restrict__ part, float* __restrict__ out, int lblk)
{
    int m = blockIdx.x * 256 + threadIdx.x;
    if (m >= NN * DD) return;
    float s = 0.0f;
    for (int b = 0; b < lblk; ++b)
        s += part[(size_t)b * (NN * DD) + m];
    out[m] = s;
}

extern "C" void kernel_launch(void* const* d_in, const int* in_sizes, int n_in,
                              void* d_out, int out_size, void* d_ws, size_t ws_size,
                              hipStream_t stream) {
    const float* x     = (const float*)d_in[0];   // [2000, 24]
    const float* alpha = (const float*)d_in[1];   // [24, 2000]
    const float* beta  = (const float*)d_in[2];   // [24, 24, 2000]
    float* out = (float*)d_out;                   // [2000, 24]
    float* part = (float*)d_ws;

    // choose number of l-chunks that fits in workspace
    int lblk = 64;
    while (lblk > 1 && (size_t)lblk * NN * DD * sizeof(float) > ws_size) lblk >>= 1;
    int lch = (NN + lblk - 1) / lblk;

    dim3 g1(32, lblk);
    notears_pass1<<<g1, 64, 0, stream>>>(x, alpha, beta, part, lblk, lch);

    int m = NN * DD;
    notears_pass2<<<(m + 255) / 256, 256, 0, stream>>>(part, out, lblk);
}

// Round 2
// 297.656 us; speedup vs baseline: 3.4823x; 3.4823x over previous
//
#include <hip/hip_runtime.h>
#include <hip/hip_bf16.h>

#define NN 2000
#define DD 24
#define JA (DD * DD)          // 576
#define WROW 640              // 576 (2*beta^T) + 24 (alpha) + 24 (2*beta diag) + pad
#define A_OFF JA              // 576
#define DIAG_OFF (JA + DD)    // 600

// ---- pre-pass: W[l][ja] = 2*beta[ja][l]  (tile transpose of a 576 x 2000 matrix)
__global__ __launch_bounds__(256) void k_transpose(const float* __restrict__ beta,
                                                   float* __restrict__ W) {
    __shared__ float t[64][65];
    const int l0 = blockIdx.x * 64, ja0 = blockIdx.y * 64;
    for (int r = threadIdx.y; r < 64; r += 4) {
        int ja = ja0 + r, l = l0 + threadIdx.x;
        if (ja < JA && l < NN) t[r][threadIdx.x] = 2.0f * beta[(size_t)ja * NN + l];
    }
    __syncthreads();
    for (int r = threadIdx.y; r < 64; r += 4) {
        int l = l0 + r, ja = ja0 + threadIdx.x;
        if (l < NN && ja < JA) W[(size_t)l * WROW + ja] = t[threadIdx.x][r];
    }
}

// ---- pre-pass: append alpha and 2*beta[j][j][l] columns to each W row
__global__ __launch_bounds__(256) void k_fill(const float* __restrict__ beta,
                                              const float* __restrict__ alpha,
                                              float* __restrict__ W) {
    int l = blockIdx.x * 256 + threadIdx.x;
    if (l >= NN) return;
    float* w = W + (size_t)l * WROW;
    #pragma unroll
    for (int j = 0; j < DD; ++j) {
        w[A_OFF + j]    = alpha[(size_t)j * NN + l];
        w[DIAG_OFF + j] = 2.0f * beta[(size_t)(j * DD + j) * NN + l];
    }
}

// ---- main: lanes -> i (256 i per block, 4 waves), l wave-uniform.
// part[lb * (NN*DD) + i*DD + j] = partial over this block's l-range.
__global__ __launch_bounds__(256) void k_pass1(const float* __restrict__ x,
                                               const float* __restrict__ W,
                                               float* __restrict__ part,
                                               int lblk, int lch) {
    const int tid = threadIdx.x;
    const int ib  = blockIdx.x;      // 0..7
    const int lb  = blockIdx.y;      // 0..lblk-1
    const int i   = ib * 256 + tid;
    const int ic  = i < NN ? i : NN - 1;

    float xi[DD];
    {
        const float4* xr = reinterpret_cast<const float4*>(x + (size_t)ic * DD);
        #pragma unroll
        for (int q = 0; q < DD / 4; ++q) {
            float4 v = xr[q];
            xi[4 * q + 0] = v.x; xi[4 * q + 1] = v.y;
            xi[4 * q + 2] = v.z; xi[4 * q + 3] = v.w;
        }
    }

    float acc[DD];
    #pragma unroll
    for (int j = 0; j < DD; ++j) acc[j] = 0.0f;

    const int l0 = lb * lch;
    const int l1 = (l0 + lch) < NN ? (l0 + lch) : NN;

    for (int l = l0; l < l1; ++l) {
        const float* __restrict__ w = W + (size_t)l * WROW;   // uniform, contiguous 2.5 KB

        // x_l wave-uniform
        float xl[DD];
        {
            const float* xr = x + (size_t)l * DD;
            #pragma unroll
            for (int k = 0; k < DD; ++k) xl[k] = xr[k];
        }

        float diff[DD];
        float S = 0.0f;
        #pragma unroll
        for (int k = 0; k < DD; ++k) {
            float d = xi[k] - xl[k];
            diff[k] = d;
            S = fmaf(d, d, S);
        }

        #pragma unroll
        for (int j = 0; j < DD; ++j) {
            float d2 = diff[j] * diff[j];
            float K  = __expf(d2 - S);            // exp(-(S - diff_j^2))
            float t  = 0.0f;
            const float* bj = w + j * DD;          // 2*beta[j][a], contiguous
            #pragma unroll
            for (int a = 0; a < DD; ++a)
                t = fmaf(bj[a], diff[a], t);       // t = 2*sum_a beta*diff
            t = fmaf(-w[DIAG_OFF + j], diff[j], t);  // drop a==j
            acc[j] = fmaf(K, w[A_OFF + j] + t, acc[j]);
        }
    }

    if (i < NN) {
        float* p = part + (size_t)lb * (NN * DD) + (size_t)i * DD;
        #pragma unroll
        for (int q = 0; q < DD / 4; ++q) {
            float4 v;
            v.x = acc[4 * q + 0]; v.y = acc[4 * q + 1];
            v.z = acc[4 * q + 2]; v.w = acc[4 * q + 3];
            reinterpret_cast<float4*>(p)[q] = v;
        }
    }
}

// ---- fallback main (round-1 style, direct beta) if workspace is too small
__global__ __launch_bounds__(64) void k_pass1_direct(const float* __restrict__ x,
                                                     const float* __restrict__ alpha,
                                                     const float* __restrict__ beta,
                                                     float* __restrict__ part,
                                                     int lblk, int lch) {
    const int lane = threadIdx.x;
    const int i = blockIdx.x * 64 + lane;
    const int ic = i < NN ? i : NN - 1;
    const int lb = blockIdx.y;
    float xi[DD];
    #pragma unroll
    for (int k = 0; k < DD; ++k) xi[k] = x[(size_t)ic * DD + k];
    float acc[DD];
    #pragma unroll
    for (int j = 0; j < DD; ++j) acc[j] = 0.0f;
    const int l0 = lb * lch;
    const int l1 = (l0 + lch) < NN ? (l0 + lch) : NN;
    for (int l = l0; l < l1; ++l) {
        float diff[DD]; float S = 0.0f;
        #pragma unroll
        for (int k = 0; k < DD; ++k) {
            float d = xi[k] - x[(size_t)l * DD + k];
            diff[k] = d; S = fmaf(d, d, S);
        }
        #pragma unroll
        for (int j = 0; j < DD; ++j) {
            float K = __expf(diff[j] * diff[j] - S);
            float t = 0.0f;
            const float* bj = beta + (size_t)j * DD * NN + l;
            #pragma unroll
            for (int a = 0; a < DD; ++a) t = fmaf(bj[(size_t)a * NN], diff[a], t);
            t = fmaf(-bj[(size_t)DD * ((size_t)j) * 0 + (size_t)j * NN], diff[j], t);
            acc[j] = fmaf(K, fmaf(2.0f, t, alpha[(size_t)j * NN + l]), acc[j]);
        }
    }
    if (i < NN) {
        float* p = part + (size_t)lb * (NN * DD) + (size_t)i * DD;
        #pragma unroll
        for (int j = 0; j < DD; ++j) p[j] = acc[j];
    }
}

// ---- reduce partials over lblk slabs
__global__ __launch_bounds__(256) void k_pass2(const float* __restrict__ part,
                                               float* __restrict__ out, int lblk) {
    int m = blockIdx.x * 256 + threadIdx.x;
    if (m >= NN * DD) return;
    float s = 0.0f;
    for (int b = 0; b < lblk; ++b)
        s += part[(size_t)b * (NN * DD) + m];
    out[m] = s;
}

extern "C" void kernel_launch(void* const* d_in, const int* in_sizes, int n_in,
                              void* d_out, int out_size, void* d_ws, size_t ws_size,
                              hipStream_t stream) {
    const float* x     = (const float*)d_in[0];   // [2000, 24]
    const float* alpha = (const float*)d_in[1];   // [24, 2000]
    const float* beta  = (const float*)d_in[2];   // [24, 24, 2000]
    float* out = (float*)d_out;                   // [2000, 24]

    const size_t WBYTES = (size_t)NN * WROW * sizeof(float);      // 5.12 MB
    const size_t SLAB   = (size_t)NN * DD * sizeof(float);        // 192 KB

    if (ws_size >= WBYTES + SLAB) {
        float* W    = (float*)d_ws;
        float* part = (float*)((char*)d_ws + WBYTES);
        int lblk = 64;
        while (lblk > 1 && WBYTES + (size_t)lblk * SLAB > ws_size) lblk >>= 1;
        int lch = (NN + lblk - 1) / lblk;

        dim3 tb(64, 4);
        k_transpose<<<dim3(32, 9), tb, 0, stream>>>(beta, W);
        k_fill<<<(NN + 255) / 256, 256, 0, stream>>>(beta, alpha, W);
        k_pass1<<<dim3(8, lblk), 256, 0, stream>>>(x, W, part, lblk, lch);
        k_pass2<<<(NN * DD + 255) / 256, 256, 0, stream>>>(part, out, lblk);
    } else {
        float* part = (float*)d_ws;
        int lblk = 64;
        while (lblk > 1 && (size_t)lblk * SLAB > ws_size) lblk >>= 1;
        int lch = (NN + lblk - 1) / lblk;
        k_pass1_direct<<<dim3(32, lblk), 64, 0, stream>>>(x, alpha, beta, part, lblk, lch);
        k_pass2<<<(NN * DD + 255) / 256, 256, 0, stream>>>(part, out, lblk);
    }
}